// Round 8
// baseline (1137.463 us; speedup 1.0000x reference)
//
#include <hip/hip_runtime.h>
#include <math.h>

typedef unsigned int u32;
typedef unsigned long long u64;
typedef short s16x8 __attribute__((ext_vector_type(8)));
typedef float f32x4 __attribute__((ext_vector_type(4)));

#define HH 128
#define WW 128
#define NPIX (128*128)
#define NANCH (NPIX*6)
#define KPRE 6000
#define KPOST 300
#define SORT_CAP 16384
#define RW 96
#define NMS_T 0.7f

#define OUT_PROB 1500
#define OUT_BBOX (1500 + 98304)

/* ---------------- ws layout (bytes) ---------------- */
#define WS_CONV1 ((size_t)0)
#define WS_XTH   ((size_t)33554432)
#define WS_WPH   ((size_t)100663296)
#define WS_BOXES ((size_t)33554432)
#define WS_SCORE (WS_BOXES + 1572864)
#define WS_KEYS  (WS_SCORE + 393216)
#define WS_TB    (WS_KEYS + 131072)
#define WS_AREA  (WS_TB + 98304)
#define WS_SUP   (WS_AREA + 24576)
#define WS_HIST  (WS_SUP + 4718592)
#define WS_CTRL  (WS_HIST + 262144)
#define WS_KEEP  (WS_CTRL + 256)
#define WS_SKEYS (WS_KEEP + 1280)
#define WS_GSUM  (WS_SKEYS + 49152)

/* s_waitcnt immediates (gfx9 encoding: [3:0]vm_lo [6:4]exp [11:8]lgkm [15:14]vm_hi) */
#define WC_VM16  0x4F70   /* vmcnt(16), lgkm/exp don't-care */
#define WC_VM0   0x0F70   /* vmcnt(0)  */
#define WC_LGKM0 0xC07F   /* lgkmcnt(0) */

__device__ __forceinline__ unsigned short f2bf(float x) {
    u32 b = __float_as_uint(x);
    u32 r = (b + 0x7FFFu + ((b >> 16) & 1u)) >> 16;
    return (unsigned short)r;
}

/* async global->LDS, 16B/lane: dest = wave-uniform base + lane*16 */
__device__ __forceinline__ void gl_lds16(const void* g, void* l) {
    __builtin_amdgcn_global_load_lds(
        (__attribute__((address_space(1))) const void*)g,
        (__attribute__((address_space(3))) void*)l,
        16, 0, 0);
}

/* ---------------- init (after conv3; aliases staging region) ---------------- */
__global__ void k_init(u32* __restrict__ hist, u32* __restrict__ ctrl,
                       int* __restrict__ keep, u64* __restrict__ keys) {
    int t = blockIdx.x * blockDim.x + threadIdx.x;
    if (t < 65536) hist[t] = 0u;
    if (t < 64)    ctrl[t] = 0u;
    if (t < 304)   keep[t] = -1;
    if (t < SORT_CAP) keys[t] = ~0ULL;
}

/* X prepass: in[c][pix] f32 -> Xth[pix][c], Xtl[pix][c] bf16 (transpose+split) */
__global__ __launch_bounds__(256) void k_xsplit(const float* __restrict__ in,
                                                unsigned short* __restrict__ xth) {
    unsigned short* xtl = xth + 16777216;
    __shared__ unsigned short Th[64][72];
    __shared__ unsigned short Tl[64][72];
    const int px0 = blockIdx.x * 64;
    const int c0  = blockIdx.y * 64;
    const int t = threadIdx.x;
    const int r = t >> 4;
    const int p4 = (t & 15) * 4;
#pragma unroll
    for (int i = 0; i < 4; ++i) {
        int cr = r + 16 * i;
        float4 v = *(const float4*)(in + (size_t)(c0 + cr) * NPIX + px0 + p4);
        float vv[4] = {v.x, v.y, v.z, v.w};
#pragma unroll
        for (int k = 0; k < 4; ++k) {
            unsigned short h = f2bf(vv[k]);
            float hf = __uint_as_float((u32)h << 16);
            unsigned short l = f2bf(vv[k] - hf);
            Th[p4 + k][cr] = h;
            Tl[p4 + k][cr] = l;
        }
    }
    __syncthreads();
    const int p = t >> 2, q = t & 3;
    unsigned short* dh = xth + (size_t)(px0 + p) * 1024 + c0 + q * 16;
    unsigned short* dl = xtl + (size_t)(px0 + p) * 1024 + c0 + q * 16;
    *(uint4*)dh       = *(const uint4*)&Th[p][q * 16];
    *(uint4*)(dh + 8) = *(const uint4*)&Th[p][q * 16 + 8];
    *(uint4*)dl       = *(const uint4*)&Tl[p][q * 16];
    *(uint4*)(dl + 8) = *(const uint4*)&Tl[p][q * 16 + 8];
}

/* W prepass: w[oc][c*9+tap] -> Wph[tap][oc][c], Wpl[...] bf16; + zero-stash */
__global__ __launch_bounds__(256) void k_wpack(const float* __restrict__ w,
                                               unsigned short* __restrict__ wph,
                                               float* __restrict__ zstash) {
    if (blockIdx.x == 0 && threadIdx.x < 128) zstash[threadIdx.x] = 0.f;
    int id = blockIdx.x * 256 + threadIdx.x;
    int oc = id >> 10, c = id & 1023;
    const float* src = w + (size_t)oc * 9216 + c * 9;
#pragma unroll
    for (int tap = 0; tap < 9; ++tap) {
        float x = src[tap];
        unsigned short h = f2bf(x);
        unsigned short l = f2bf(x - __uint_as_float((u32)h << 16));
        wph[(size_t)tap * 524288 + id] = h;
        wph[4718592 + (size_t)tap * 524288 + id] = l;
    }
}

struct Frags { s16x8 ah[4], al[4], bh[4], bl[4]; };

/* conv3 via MFMA — barrier-free, wave-private dual-buffer vmcnt pipeline.
   Grid (4 ocg, 128 y, 2 xh); block = 2 waves = 128oc x 64px.
   Wave tile = 64oc x 64px (4x4 of 16x16). 288 stages = 9 taps x 32 channels.
   Per stage per wave: 16 global_load_lds (own 16KB buffer), 16 ds_read_b128,
   48 MFMA on pre-read register frags. No __syncthreads in the K-loop:
   LDS is wave-private; pipeline via s_waitcnt vmcnt(16)/lgkmcnt(0).
   Granule swizzle (lane&3)^((row>>1)&3) on the DMA source (involution,
   0 conflicts measured in R6/R7). Edge taps fed from 512B zero-stash. */
__global__ __launch_bounds__(128, 1) void k_conv3m(const unsigned short* __restrict__ xt,
                                                   const unsigned short* __restrict__ wp,
                                                   const float* __restrict__ bias,
                                                   const unsigned short* __restrict__ zst,
                                                   float* __restrict__ out) {
    const int ocg = blockIdx.x;      /* 0..3 -> XCD-pinned */
    const int y   = blockIdx.y;      /* 0..127 */
    const int xh  = blockIdx.z;      /* 0..1   */
    const int tid = threadIdx.x;     /* 0..127 */
    const int lane = tid & 63;
    const int w    = tid >> 6;       /* 0..1 = oc-half */
    const int l15  = lane & 15;
    const int quad = lane >> 4;
    const int oc0w = ocg * 128 + w * 64;
    const int px0w = xh * 64;

    __shared__ __align__(16) unsigned short Lds[32768];   /* 64 KB */
    unsigned short* WB = &Lds[w * 16384];   /* per-wave 32KB: 2 buffers x 8192 u16
        buffer: Ahi [0,2048) 64oc x 32c | Alo [2048,4096)
                Bhi [4096,6144) 64px x 32c | Blo [6144,8192) */

    const int lr  = lane >> 2;       /* row-within-16 this lane stages */
    const int lg  = lane & 3;        /* LDS granule position this lane fills */
    const int csw = lg ^ ((lr >> 1) & 3);   /* source channel granule (involution) */

    const unsigned short* src[16];
    int step[16];

    auto set_tap = [&](int tap) {
        const int dy = tap / 3, dx = tap - dy * 3;
        const int yy = y + dy - 1;
        const bool yok = (yy >= 0) && (yy < HH);
#pragma unroll
        for (int j = 0; j < 8; ++j) {            /* A = W slice */
            const int pl  = j >> 2;
            const int row = (j & 3) * 16 + lr;
            src[j]  = wp + (size_t)pl * 4718592 + (size_t)tap * 524288
                         + (size_t)(oc0w + row) * 1024 + csw * 8;
            step[j] = 32;
        }
#pragma unroll
        for (int j = 8; j < 16; ++j) {           /* B = X slice (dx-shifted) */
            const int pl = (j >> 2) & 1;
            const int p  = (j & 3) * 16 + lr;
            const int x  = px0w - 1 + dx + p;
            const bool ok = yok && (x >= 0) && (x < WW);
            src[j]  = ok ? xt + (size_t)pl * 16777216
                              + (size_t)(yy * WW + x) * 1024 + csw * 8
                         : zst + lg * 8;
            step[j] = ok ? 32 : 0;
        }
    };

    auto issue = [&](int buf) {
        unsigned short* db = WB + buf * 8192;
#pragma unroll
        for (int j = 0; j < 16; ++j) {
            gl_lds16(src[j], db + j * 512);
            src[j] += step[j];
        }
    };

    const int g  = quad ^ ((l15 >> 1) & 3);
    const int ra = l15 * 32 + g * 8;

    auto readf = [&](Frags& F, const unsigned short* rb) {
#pragma unroll
        for (int og = 0; og < 4; ++og) {
            F.ah[og] = *(const s16x8*)&rb[ra + og * 512];
            F.al[og] = *(const s16x8*)&rb[ra + 2048 + og * 512];
        }
#pragma unroll
        for (int nt = 0; nt < 4; ++nt) {
            F.bh[nt] = *(const s16x8*)&rb[ra + 4096 + nt * 512];
            F.bl[nt] = *(const s16x8*)&rb[ra + 6144 + nt * 512];
        }
    };

    f32x4 acc[4][4];
#pragma unroll
    for (int og = 0; og < 4; ++og)
#pragma unroll
        for (int nt = 0; nt < 4; ++nt) acc[og][nt] = (f32x4){0.f, 0.f, 0.f, 0.f};

    auto domfma = [&](Frags& F) {
#pragma unroll
        for (int nt = 0; nt < 4; ++nt)
#pragma unroll
            for (int og = 0; og < 4; ++og) {
                acc[og][nt] = __builtin_amdgcn_mfma_f32_16x16x32_bf16(F.ah[og], F.bh[nt], acc[og][nt], 0, 0, 0);
                acc[og][nt] = __builtin_amdgcn_mfma_f32_16x16x32_bf16(F.ah[og], F.bl[nt], acc[og][nt], 0, 0, 0);
                acc[og][nt] = __builtin_amdgcn_mfma_f32_16x16x32_bf16(F.al[og], F.bh[nt], acc[og][nt], 0, 0, 0);
            }
    };

    Frags FA, FB;

    auto stage = [&](int s, Frags& Fc, Frags& Fn) {
        const int cur = s & 1;
        /* guard: frags(s) reads (issued last stage from buf cur) have landed
           in VGPRs before DMA overwrites buf cur */
        __builtin_amdgcn_s_waitcnt(WC_LGKM0);
        if (s + 2 < 288) {
            if (((s + 2) & 31) == 0) set_tap((s + 2) >> 5);
            issue(cur);                               /* for stage s+2 */
            __builtin_amdgcn_s_waitcnt(WC_VM16);      /* buf(s+1) DMAs done */
        } else {
            __builtin_amdgcn_s_waitcnt(WC_VM0);
        }
        if (s + 1 < 288) readf(Fn, WB + (cur ^ 1) * 8192);
        domfma(Fc);                                   /* regs only: issues at once */
    };

    set_tap(0);
    issue(0);
    issue(1);
    __builtin_amdgcn_s_waitcnt(WC_VM16);   /* buf0 ready */
    readf(FA, WB);

#pragma unroll 1
    for (int sp = 0; sp < 144; ++sp) {
        stage(2 * sp,     FA, FB);
        stage(2 * sp + 1, FB, FA);
    }

    /* epilogue: D row(oc) = quad*4+rg, col(px) = l15 */
#pragma unroll
    for (int og = 0; og < 4; ++og)
#pragma unroll
        for (int nt = 0; nt < 4; ++nt)
#pragma unroll
            for (int rg = 0; rg < 4; ++rg) {
                const int oc = oc0w + og * 16 + quad * 4 + rg;
                const int px = px0w + nt * 16 + l15;
                float v = acc[og][nt][rg] + bias[oc];
                out[(size_t)oc * NPIX + y * WW + px] = fmaxf(v, 0.f);
            }
}

/* ---------------- fused 1x1 convs + pair softmax ---------------- */
__global__ __launch_bounds__(256) void k_conv1(const float* __restrict__ conv1,
                                               const float* __restrict__ wcls,
                                               const float* __restrict__ bcls,
                                               const float* __restrict__ wbox,
                                               const float* __restrict__ bboxb,
                                               float* __restrict__ out) {
    const int tid = threadIdx.x;
    const int og = tid >> 4, pg = tid & 15;
    const int px0 = blockIdx.x * 64;
    __shared__ __align__(16) float Wl[32][32];
    __shared__ __align__(16) float Xl[32][64];
    __shared__ float Sc[6][64];

    float a0[4] = {0, 0, 0, 0}, a1[4] = {0, 0, 0, 0};

    for (int cc = 0; cc < 16; ++cc) {
        {
            int u = tid;
            int row = (u * 4) >> 5;
            int col = (u * 4) & 31;
            float4 v;
            if (row < 6)       v = *(const float4*)(wcls + row * 512 + cc * 32 + col);
            else if (row < 30) v = *(const float4*)(wbox + (row - 6) * 512 + cc * 32 + col);
            else               v = make_float4(0.f, 0.f, 0.f, 0.f);
            *(float4*)&Wl[row][col] = v;
        }
        for (int u = tid; u < 512; u += 256) {
            int row = (u * 4) >> 6, col = (u * 4) & 63;
            *(float4*)&Xl[row][col] =
                *(const float4*)(conv1 + (size_t)(cc * 32 + row) * NPIX + px0 + col);
        }
        __syncthreads();
#pragma unroll
        for (int cp = 0; cp < 32; ++cp) {
            const float4 x = *(const float4*)&Xl[cp][pg * 4];
            const float w0 = Wl[og][cp];
            const float w1 = Wl[og + 16][cp];
            a0[0] = fmaf(w0, x.x, a0[0]); a0[1] = fmaf(w0, x.y, a0[1]);
            a0[2] = fmaf(w0, x.z, a0[2]); a0[3] = fmaf(w0, x.w, a0[3]);
            a1[0] = fmaf(w1, x.x, a1[0]); a1[1] = fmaf(w1, x.y, a1[1]);
            a1[2] = fmaf(w1, x.z, a1[2]); a1[3] = fmaf(w1, x.w, a1[3]);
        }
        __syncthreads();
    }
    const int pxb = px0 + pg * 4;
    if (og < 6) {
        const float bc = bcls[og];
#pragma unroll
        for (int kk = 0; kk < 4; ++kk) Sc[og][pg * 4 + kk] = a0[kk] + bc;
    } else {
        const float bb = bboxb[og - 6];
#pragma unroll
        for (int kk = 0; kk < 4; ++kk)
            out[OUT_BBOX + (size_t)(og - 6) * NPIX + pxb + kk] = a0[kk] + bb;
    }
    if (og + 16 < 30) {
        const float bb = bboxb[og + 10];
#pragma unroll
        for (int kk = 0; kk < 4; ++kk)
            out[OUT_BBOX + (size_t)(og + 10) * NPIX + pxb + kk] = a1[kk] + bb;
    }
    __syncthreads();
    if (og < 6) {
        const int pa = og < 3 ? og + 3 : og - 3;
#pragma unroll
        for (int kk = 0; kk < 4; ++kk) {
            const float s = Sc[og][pg * 4 + kk], sp = Sc[pa][pg * 4 + kk];
            out[OUT_PROB + (size_t)og * NPIX + pxb + kk] = 1.0f / (1.0f + expf(sp - s));
        }
    }
}

/* ---------------- anchor decode + clip + histogram (fused) ---------------- */
__global__ void k_decode(const float* __restrict__ out, const float* __restrict__ meta,
                         float4* __restrict__ boxes, float* __restrict__ scores,
                         u32* __restrict__ hist) {
#pragma clang fp contract(off)
    int t = blockIdx.x * blockDim.x + threadIdx.x;
    if (t >= NANCH) return;
    int a = t >> 14;
    int pix = t & 16383;
    int yc = pix >> 7, xc = pix & 127;
    int n = pix * 6 + a;
    float sc = out[OUT_PROB + (size_t)a * NPIX + pix];
    float d0 = out[OUT_BBOX + (size_t)(a * 4 + 0) * NPIX + pix];
    float d1 = out[OUT_BBOX + (size_t)(a * 4 + 1) * NPIX + pix];
    float d2 = out[OUT_BBOX + (size_t)(a * 4 + 2) * NPIX + pix];
    float d3 = out[OUT_BBOX + (size_t)(a * 4 + 3) * NPIX + pix];
    const float dims = (float)(16 << a);
    const float cxa = (xc + 0.5f) * 16.f;
    const float cya = (yc + 0.5f) * 16.f;
    float pcx = d0 * dims + cxa;
    float pcy = d1 * dims + cya;
    float pw  = expf(d2) * dims;
    float ph  = expf(d3) * dims;
    float imh = meta[0], imw = meta[1];
    float x1 = fminf(fmaxf(pcx - 0.5f * pw, 0.f), imw);
    float y1 = fminf(fmaxf(pcy - 0.5f * ph, 0.f), imh);
    float x2 = fminf(fmaxf(pcx + 0.5f * pw, 0.f), imw);
    float y2 = fminf(fmaxf(pcy + 0.5f * ph, 0.f), imh);
    boxes[n] = make_float4(x1, y1, x2, y2);
    scores[n] = sc;
    atomicAdd(&hist[__float_as_uint(sc) >> 16], 1u);
}

/* ---------------- select: 2-phase parallel threshold find ---------------- */
__global__ __launch_bounds__(256) void k_select1(const u32* __restrict__ hist,
                                                 u32* __restrict__ gsum) {
    __shared__ u32 red[256];
    const int t = threadIdx.x;
    red[t] = hist[blockIdx.x * 256 + t];
    __syncthreads();
    for (int s = 128; s > 0; s >>= 1) {
        if (t < s) red[t] += red[t + s];
        __syncthreads();
    }
    if (t == 0) gsum[blockIdx.x] = red[0];
}

__global__ void k_select2(const u32* __restrict__ hist, const u32* __restrict__ gsum,
                          u32* __restrict__ ctrl) {
    __shared__ u32 S[256];
    __shared__ u32 U[256];
    __shared__ u32 Hh[256];
    __shared__ int gsel;
    const int t = threadIdx.x;
    S[t] = gsum[t];
    __syncthreads();
    if (t == 0) {
        u32 acc = 0;
        for (int g2 = 255; g2 >= 0; --g2) { U[g2] = acc; acc += S[g2]; }
    }
    __syncthreads();
    if (U[t] < KPRE && U[t] + S[t] >= KPRE) gsel = t;
    __syncthreads();
    const int g = gsel;
    Hh[t] = hist[g * 256 + t];
    __syncthreads();
    if (t == 0) {
        u32 acc = U[g];
        for (int b2 = 255; b2 >= 0; --b2) {
            u32 h = Hh[b2];
            if (acc + h >= KPRE) { ctrl[1] = (u32)(g * 256 + b2); ctrl[2] = acc; break; }
            acc += h;
        }
    }
}

__global__ void k_compact(const float* __restrict__ scores, u32* __restrict__ ctrl,
                          u64* __restrict__ keys) {
    int t = blockIdx.x * blockDim.x + threadIdx.x;
    if (t >= NANCH) return;
    u32 bits = __float_as_uint(scores[t]);
    if ((bits >> 16) >= ctrl[1]) {
        u32 pos = atomicAdd(&ctrl[0], 1u);
        if (pos < SORT_CAP) keys[pos] = ((u64)(~bits) << 32) | (u32)t;
    }
}

__global__ __launch_bounds__(1024) void k_sort_local(u64* __restrict__ keys) {
    __shared__ u64 lds[8192];
    const int tid = threadIdx.x;
    u64* g = keys + blockIdx.x * 8192;
    for (int u = tid; u < 8192; u += 1024) lds[u] = g[u];
    __syncthreads();
    for (int k = 2; k <= 8192; k <<= 1) {
        for (int j = k >> 1; j > 0; j >>= 1) {
            for (int u = tid; u < 4096; u += 1024) {
                int i = ((u & ~(j - 1)) << 1) | (u & (j - 1));
                int l = i | j;
                bool up = (i & k) == 0;
                u64 x = lds[i], y2 = lds[l];
                if ((x > y2) == up) { lds[i] = y2; lds[l] = x; }
            }
            __syncthreads();
        }
    }
    for (int u = tid; u < 8192; u += 1024) g[u] = lds[u];
}

__global__ void k_merge(const u64* __restrict__ keys, u64* __restrict__ skeys) {
    int i = blockIdx.x * blockDim.x + threadIdx.x;
    if (i >= KPRE) return;
    const u64* A = keys;
    const u64* B = keys + 8192;
    int lo = i > 8192 ? i - 8192 : 0;
    int hi = i < 8192 ? i : 8192;
    while (lo < hi) {
        int a = (lo + hi) >> 1;
        if (A[a] < B[i - a - 1]) lo = a + 1; else hi = a;
    }
    int a = lo, b = i - lo;
    u64 va = (a < 8192) ? A[a] : ~0ULL;
    u64 vb = (b < 8192) ? B[b] : ~0ULL;
    skeys[i] = va < vb ? va : vb;
}

__global__ void k_gather(const u64* __restrict__ skeys, const float4* __restrict__ boxes,
                         float4* __restrict__ tb, float* __restrict__ areas) {
#pragma clang fp contract(off)
    int i = blockIdx.x * blockDim.x + threadIdx.x;
    if (i >= KPRE) return;
    u32 n = (u32)(skeys[i] & 0xFFFFFFFFULL);
    float4 b = boxes[n];
    tb[i] = b;
    areas[i] = fmaxf(b.z - b.x, 0.f) * fmaxf(b.w - b.y, 0.f);
}

__global__ __launch_bounds__(256) void k_bitmap(const float4* __restrict__ tb,
                                                const float* __restrict__ areas,
                                                u64* __restrict__ suppr) {
#pragma clang fp contract(off)
    const int i = blockIdx.x;
    const int lane = threadIdx.x & 63;
    const int wv = threadIdx.x >> 6;
    const float4 bi = tb[i];
    const float ai = areas[i];
    for (int Wd = wv; Wd < RW; Wd += 4) {
        int j = Wd * 64 + lane;
        bool sup = false;
        if (j < KPRE) {
            float4 bj = tb[j];
            float iw = fmaxf(fminf(bi.z, bj.z) - fmaxf(bi.x, bj.x), 0.f);
            float ih = fmaxf(fminf(bi.w, bj.w) - fmaxf(bi.y, bj.y), 0.f);
            float inter = iw * ih;
            float denom = ((areas[j] + ai) - inter) + 1e-9f;
            sup = (inter / denom) > NMS_T;
        }
        u64 m = __ballot(sup);
        if (lane == 0) suppr[(size_t)i * RW + Wd] = m;
    }
}

/* greedy scan with 1-deep speculative row prefetch (exact NMS semantics) */
__global__ void k_scan(const u64* __restrict__ suppr, int* __restrict__ keep) {
    const int lane = threadIdx.x;   /* 64 threads */
    u64 a0 = (lane < 93) ? ~0ULL : (lane == 93 ? ((1ULL << 48) - 1) : 0ULL);
    const int w1 = lane + 64;
    u64 a1 = (w1 < 93) ? ~0ULL : (w1 == 93 ? ((1ULL << 48) - 1) : 0ULL);

    auto nexta = [&](int i) -> int {
        int p = i + 1;
        int wi = p >> 6, off = p & 63;
        while (wi < 94) {
            u64 wv = (wi < 64) ? __shfl(a0, wi) : __shfl(a1, wi - 64);
            wv &= (~0ULL) << off;
            if (wv) return (wi << 6) + __ffsll((long long)wv) - 1;
            ++wi; off = 0;
        }
        return -1;
    };

    int i = 0;     /* top-scoring box: always alive first */
    u64 r0 = suppr[lane];
    u64 r1 = (lane + 64 < RW) ? suppr[lane + 64] : 0ULL;
    int kept = 0;
    while (true) {
        if (lane == 0) keep[kept] = i;
        kept++;
        if (kept >= KPOST) break;
        int i2 = nexta(i);                 /* pre-apply candidate */
        u64 p0 = 0, p1 = 0;
        if (i2 >= 0) {                     /* speculative load (usually hits) */
            p0 = suppr[(size_t)i2 * RW + lane];
            p1 = (lane + 64 < RW) ? suppr[(size_t)i2 * RW + lane + 64] : 0ULL;
        }
        a0 &= ~r0; a1 &= ~r1;              /* apply row i */
        int j = nexta(i);                  /* post-apply next kept */
        if (j < 0) break;
        if (j == i2) { r0 = p0; r1 = p1; }
        else {
            r0 = suppr[(size_t)j * RW + lane];
            r1 = (lane + 64 < RW) ? suppr[(size_t)j * RW + lane + 64] : 0ULL;
        }
        i = j;
    }
}

__global__ void k_rois(const int* __restrict__ keep, const float4* __restrict__ tb,
                       float* __restrict__ out) {
    int r = blockIdx.x * blockDim.x + threadIdx.x;
    if (r >= KPOST) return;
    int k = keep[r];
    float4 b = make_float4(0.f, 0.f, 0.f, 0.f);
    if (k >= 0) b = tb[k];
    out[r * 5 + 0] = 0.f;
    out[r * 5 + 1] = b.x;
    out[r * 5 + 2] = b.y;
    out[r * 5 + 3] = b.z;
    out[r * 5 + 4] = b.w;
}

extern "C" void kernel_launch(void* const* d_in, const int* in_sizes, int n_in,
                              void* d_out, int out_size, void* d_ws, size_t ws_size,
                              hipStream_t stream) {
    (void)in_sizes; (void)n_in; (void)out_size; (void)ws_size;
    const float* x     = (const float*)d_in[0];
    const float* meta  = (const float*)d_in[1];
    const float* wc3   = (const float*)d_in[3];
    const float* bc3   = (const float*)d_in[4];
    const float* wcls  = (const float*)d_in[5];
    const float* bcls  = (const float*)d_in[6];
    const float* wbox  = (const float*)d_in[7];
    const float* bboxb = (const float*)d_in[8];
    float* out = (float*)d_out;
    char* ws = (char*)d_ws;

    float*  conv1  = (float*)(ws + WS_CONV1);
    float4* boxes  = (float4*)(ws + WS_BOXES);
    float*  scores = (float*)(ws + WS_SCORE);
    u64*    keys   = (u64*)(ws + WS_KEYS);
    float4* tb     = (float4*)(ws + WS_TB);
    float*  areas  = (float*)(ws + WS_AREA);
    u64*    suppr  = (u64*)(ws + WS_SUP);
    u32*    hist   = (u32*)(ws + WS_HIST);
    u32*    ctrl   = (u32*)(ws + WS_CTRL);
    int*    keep   = (int*)(ws + WS_KEEP);
    u64*    skeys  = (u64*)(ws + WS_SKEYS);
    u32*    gsum   = (u32*)(ws + WS_GSUM);

    float* zstash = out;   /* 512B zeros; rewritten by k_rois at the end */

    unsigned short* xth = (unsigned short*)(ws + WS_XTH);
    unsigned short* wph = (unsigned short*)(ws + WS_WPH);
    k_xsplit<<<dim3(256, 16), 256, 0, stream>>>(x, xth);
    k_wpack<<<2048, 256, 0, stream>>>(wc3, wph, zstash);
    k_conv3m<<<dim3(4, 128, 2), 128, 0, stream>>>(xth, wph, bc3,
                                                  (const unsigned short*)zstash, conv1);

    k_init<<<256, 256, 0, stream>>>(hist, ctrl, keep, keys);
    k_conv1<<<256, 256, 0, stream>>>(conv1, wcls, bcls, wbox, bboxb, out);
    k_decode<<<384, 256, 0, stream>>>(out, meta, boxes, scores, hist);
    k_select1<<<256, 256, 0, stream>>>(hist, gsum);
    k_select2<<<1, 256, 0, stream>>>(hist, gsum, ctrl);
    k_compact<<<384, 256, 0, stream>>>(scores, ctrl, keys);
    k_sort_local<<<2, 1024, 0, stream>>>(keys);
    k_merge<<<24, 256, 0, stream>>>(keys, skeys);
    k_gather<<<24, 256, 0, stream>>>(skeys, boxes, tb, areas);
    k_bitmap<<<6000, 256, 0, stream>>>(tb, areas, suppr);
    k_scan<<<1, 64, 0, stream>>>(suppr, keep);
    k_rois<<<2, 256, 0, stream>>>(keep, tb, out);
}